// Round 11
// baseline (1626.977 us; speedup 1.0000x reference)
//
#include <hip/hip_runtime.h>
#include <hip/hip_bf16.h>
#include <cstdint>

#define NT   900
#define EMB  1152
#define NH   16
#define DHD  72
#define DHH  36
#define DHP  96      // padded head dim (3*32)
#define KVP  928     // padded kv length (29*32)
#define NL   6
#define FFD  4608
#define MHD  4608
#define OUTD 2048
#define NM   225

typedef __attribute__((ext_vector_type(8))) short short8;
typedef __attribute__((ext_vector_type(4))) float f32x4;

__device__ __forceinline__ ushort f2bf(float f) {
    uint32_t u = __float_as_uint(f);
    uint32_t r = u + 0x7FFF + ((u >> 16) & 1);
    return (ushort)(r >> 16);
}
__device__ __forceinline__ float gelu_f(float x) {
    return 0.5f * x * (1.0f + tanhf(0.7978845608f * (x + 0.044715f * x * x * x)));
}

// async global -> LDS, 16B per lane (lds dest must be wave-uniform base; HW adds lane*16)
__device__ __forceinline__ void g2lds16(const ushort* g, ushort* l) {
    __builtin_amdgcn_global_load_lds(
        (const __attribute__((address_space(1))) unsigned int*)g,
        (__attribute__((address_space(3))) unsigned int*)l, 16, 0, 0);
}

// ---------------- weight f32 -> bf16 pre-conversion ----------------
__global__ __launch_bounds__(256) void k_cvt(const float* __restrict__ src,
                                             ushort* __restrict__ dst, int n4) {
    int idx = blockIdx.x * 256 + threadIdx.x;
    if (idx >= n4) return;
    const float4 v = *(const float4*)(src + (size_t)idx * 4);
    ushort o[4] = { f2bf(v.x), f2bf(v.y), f2bf(v.z), f2bf(v.w) };
    *(uint2*)(dst + (size_t)idx * 4) = *(const uint2*)o;
}

// ---------------- patch extraction: pixels -> bf16 [900, 1536] ----------------
__global__ __launch_bounds__(256) void k_patch(const float* __restrict__ pix,
                                               ushort* __restrict__ xp) {
    int idx = blockIdx.x * 256 + threadIdx.x;
    if (idx >= NT * 1536) return;
    int t = idx / 1536, f = idx - t * 1536;
    int mw = t & 1, mh = (t >> 1) & 1;
    int tq = t >> 2;
    int jj = tq % 15, ii = tq / 15;
    int pw = f & 15, ph = (f >> 4) & 15, c = f >> 9;
    int Hi = (ii * 2 + mh) * 16 + ph;
    int Wi = (jj * 2 + mw) * 16 + pw;
    float p = pix[((size_t)c * 480 + Hi) * 480 + Wi];
    xp[idx] = f2bf((p - 127.5f) * (1.0f / 127.5f));
}

// ---------------- layernorm f32 in -> bf16 out, one block per row ----------------
__global__ __launch_bounds__(256) void k_ln(const float* __restrict__ x,
                                            const float* __restrict__ w,
                                            const float* __restrict__ b,
                                            ushort* __restrict__ y, int C) {
    int row = blockIdx.x;
    int tid = threadIdx.x;
    const float* xr = x + (size_t)row * C;
    float s = 0.f, ss = 0.f;
    for (int c = tid; c < C; c += 256) { float v = xr[c]; s += v; ss += v * v; }
    for (int off = 32; off; off >>= 1) {
        s  += __shfl_down(s,  off, 64);
        ss += __shfl_down(ss, off, 64);
    }
    __shared__ float rs[4], rss[4];
    int wid = tid >> 6, lane = tid & 63;
    if (lane == 0) { rs[wid] = s; rss[wid] = ss; }
    __syncthreads();
    float S  = rs[0] + rs[1] + rs[2] + rs[3];
    float SS = rss[0] + rss[1] + rss[2] + rss[3];
    float mu  = S / C;
    float var = SS / C - mu * mu;
    float inv = rsqrtf(var + 1e-6f);
    ushort* yr = y + (size_t)row * C;
    for (int c = tid; c < C; c += 256) yr[c] = f2bf((xr[c] - mu) * inv * w[c] + b[c]);
}

// ---------------- dense MFMA GEMM, 64x64 tile, BK=64, global_load_lds + XOR swizzle
// + double-buffered LDS, ONE barrier per K-step (T3 minimum 2-phase).
// C[M,N] = act(A[M,K](bf16) @ W[N,K]^T(bf16) + bias) + res   (N % 64 == 0)
// LDS physical layout: row r, granule g (8 elems) holds global granule g ^ (r&7).
template <int ACT, int OBF16, int SPLIT>
__global__ __launch_bounds__(256) void k_bgs(const ushort* __restrict__ A,
                                             const ushort* __restrict__ W,
                                             const float* __restrict__ bias,
                                             const float* __restrict__ res,
                                             void* __restrict__ Cp,
                                             float* __restrict__ part,
                                             int M, int N, int K, int S) {
    __shared__ __align__(16) ushort As[2][64 * 64];
    __shared__ __align__(16) ushort Bs[2][64 * 64];
    int tid = threadIdx.x;
    int row0 = blockIdx.x * 64, col0 = blockIdx.y * 64;
    int z = blockIdx.z;
    int Kc = K / S;              // multiple of 64
    int kbeg = z * Kc;
    int steps = Kc >> 6;

    int w = tid >> 6, lane = tid & 63;
    int lrow = lane >> 3;                    // 0..7
    int cg   = ((lane & 7) ^ lrow) << 3;     // pre-swizzled source granule (elems)

    // staging rows: wave w covers rows [w*16, w*16+16) in two 8-row issues
    int ar0 = row0 + w * 16 + lrow; if (ar0 > M - 1) ar0 = M - 1;
    int ar1 = row0 + w * 16 + 8 + lrow; if (ar1 > M - 1) ar1 = M - 1;
    int wr0 = col0 + w * 16 + lrow;          // N multiple of 64 -> in range
    int wr1 = wr0 + 8;
    const ushort* ap0 = A + (size_t)ar0 * K + kbeg + cg;
    const ushort* ap1 = A + (size_t)ar1 * K + kbeg + cg;
    const ushort* wp0 = W + (size_t)wr0 * K + kbeg + cg;
    const ushort* wp1 = W + (size_t)wr1 * K + kbeg + cg;
    int ld0 = (w * 16) * 64;
    int ld1 = (w * 16 + 8) * 64;

    int fr = lane & 15, kg8 = (lane >> 4) << 3;
    int wrr = (w >> 1) * 32, wcc = (w & 1) * 32;
    int sw = (fr & 7) << 3;                  // ds_read granule XOR (elems)

    f32x4 acc[2][2] = {};
    // prologue: stage tile 0 into buffer 0
    g2lds16(ap0, &As[0][ld0]);
    g2lds16(ap1, &As[0][ld1]);
    g2lds16(wp0, &Bs[0][ld0]);
    g2lds16(wp1, &Bs[0][ld1]);
    __syncthreads();                         // vmcnt(0) drained: tile 0 resident

    int cur = 0;
    for (int s = 0; s < steps; ++s) {
        // issue next tile's DMA into the other buffer (overlaps with compute below)
        if (s + 1 < steps) {
            int kk = (s + 1) << 6;
            int nb = cur ^ 1;
            g2lds16(ap0 + kk, &As[nb][ld0]);
            g2lds16(ap1 + kk, &As[nb][ld1]);
            g2lds16(wp0 + kk, &Bs[nb][ld0]);
            g2lds16(wp1 + kk, &Bs[nb][ld1]);
        }
        // compute current tile
#pragma unroll
        for (int j = 0; j < 2; ++j) {
            int ko = j * 32 + kg8;
            int kx = ko ^ sw;
            short8 a0 = *(const short8*)&As[cur][(wrr + fr) * 64 + kx];
            short8 a1 = *(const short8*)&As[cur][(wrr + 16 + fr) * 64 + kx];
            short8 b0 = *(const short8*)&Bs[cur][(wcc + fr) * 64 + kx];
            short8 b1 = *(const short8*)&Bs[cur][(wcc + 16 + fr) * 64 + kx];
            acc[0][0] = __builtin_amdgcn_mfma_f32_16x16x32_bf16(a0, b0, acc[0][0], 0, 0, 0);
            acc[0][1] = __builtin_amdgcn_mfma_f32_16x16x32_bf16(a0, b1, acc[0][1], 0, 0, 0);
            acc[1][0] = __builtin_amdgcn_mfma_f32_16x16x32_bf16(a1, b0, acc[1][0], 0, 0, 0);
            acc[1][1] = __builtin_amdgcn_mfma_f32_16x16x32_bf16(a1, b1, acc[1][1], 0, 0, 0);
        }
        __syncthreads();                     // drains vmcnt/lgkm: next tile resident, reads done
        cur ^= 1;
    }

#pragma unroll
    for (int fi = 0; fi < 2; fi++)
#pragma unroll
        for (int fj = 0; fj < 2; fj++)
#pragma unroll
            for (int r = 0; r < 4; r++) {
                int row = row0 + wrr + fi * 16 + (lane >> 4) * 4 + r;
                int col = col0 + wcc + fj * 16 + fr;
                if (row < M) {
                    if (SPLIT) {
                        part[((size_t)z * M + row) * N + col] = acc[fi][fj][r];
                    } else {
                        float v = acc[fi][fj][r] + bias[col];
                        if (res) v += res[(size_t)row * N + col];
                        if (ACT == 1) v = gelu_f(v);
                        if (OBF16) ((ushort*)Cp)[(size_t)row * N + col] = f2bf(v);
                        else       ((float*)Cp)[(size_t)row * N + col] = v;
                    }
                }
            }
}

// ---------------- split-K fixup ----------------
template <int ACT, int OBF16>
__global__ __launch_bounds__(256) void k_fix(const float* __restrict__ part,
                                             const float* __restrict__ bias,
                                             const float* __restrict__ res,
                                             void* __restrict__ Cp,
                                             int M, int N, int S) {
    size_t idx = (size_t)blockIdx.x * 256 + threadIdx.x;
    size_t total = (size_t)M * N / 4;
    if (idx >= total) return;
    size_t e = idx * 4;
    int row = (int)(e / N), col = (int)(e - (size_t)row * N);
    float4 v = *(const float4*)(part + e);
    for (int s = 1; s < S; ++s) {
        const float4 p = *(const float4*)(part + (size_t)s * M * N + e);
        v.x += p.x; v.y += p.y; v.z += p.z; v.w += p.w;
    }
    const float4 bi = *(const float4*)(bias + col);
    v.x += bi.x; v.y += bi.y; v.z += bi.z; v.w += bi.w;
    if (res) {
        const float4 rr = *(const float4*)(res + e);
        v.x += rr.x; v.y += rr.y; v.z += rr.z; v.w += rr.w;
    }
    if (ACT == 1) { v.x = gelu_f(v.x); v.y = gelu_f(v.y); v.z = gelu_f(v.z); v.w = gelu_f(v.w); }
    if (OBF16) {
        ushort o[4] = { f2bf(v.x), f2bf(v.y), f2bf(v.z), f2bf(v.w) };
        *(uint2*)((ushort*)Cp + e) = *(const uint2*)o;
    } else {
        *(float4*)((float*)Cp + e) = v;
    }
}

// ---------------- attention GEMM (bf16 A & W, batched over heads), BK=32,
// register-prefetch double-buffer (R4-proven pattern) ----
template <int OBF16>
__global__ __launch_bounds__(256) void k_mm(const ushort* __restrict__ A,
                                            const ushort* __restrict__ Wb,
                                            void* __restrict__ Cp,
                                            int M, int N, int K, int ldc, int Nw,
                                            long as_, long ws_, long cs_) {
    __shared__ __align__(16) ushort As[64 * 40];
    __shared__ __align__(16) ushort Bs[64 * 40];
    int z = blockIdx.z;
    A  += (size_t)z * as_;
    Wb += (size_t)z * ws_;
    float*  Cf = (float*)Cp + (size_t)z * cs_;
    ushort* Cb = (ushort*)Cp + (size_t)z * cs_;

    int tid = threadIdx.x;
    int row0 = blockIdx.y * 64, col0 = blockIdx.x * 64;

    int sm = tid >> 2, sp = tid & 3;
    int ar = row0 + sm; if (ar > M - 1) ar = M - 1;
    int wr = col0 + sm; if (wr > N - 1) wr = N - 1;
    const ushort* aptr = A + (size_t)ar * K + sp * 8;
    const ushort* wptr = Wb + (size_t)wr * K + sp * 8;
    ushort* asd = &As[sm * 40 + sp * 8];
    ushort* bsd = &Bs[sm * 40 + sp * 8];

    int lane = tid & 63, wid = tid >> 6;
    int wrr = (wid >> 1) * 32, wcc = (wid & 1) * 32;
    int fr = lane & 15, kg = lane >> 4;

    f32x4 acc[2][2] = {};
    uint4 ra = *(const uint4*)aptr;
    uint4 rb = *(const uint4*)wptr;

    for (int k0 = 0; k0 < K; k0 += 32) {
        __syncthreads();                 // prior tile's reads complete
        *(uint4*)asd = ra;
        *(uint4*)bsd = rb;
        if (k0 + 32 < K) {
            ra = *(const uint4*)(aptr + k0 + 32);
            rb = *(const uint4*)(wptr + k0 + 32);
        }
        __syncthreads();
        short8 a0 = *(const short8*)&As[(wrr + fr) * 40 + kg * 8];
        short8 a1 = *(const short8*)&As[(wrr + 16 + fr) * 40 + kg * 8];
        short8 b0 = *(const short8*)&Bs[(wcc + fr) * 40 + kg * 8];
        short8 b1 = *(const short8*)&Bs[(wcc + 16 + fr) * 40 + kg * 8];
        acc[0][0] = __builtin_amdgcn_mfma_f32_16x16x32_bf16(a0, b0, acc[0][0], 0, 0, 0);
        acc[0][1] = __builtin_amdgcn_mfma_f32_16x16x32_bf16(a0, b1, acc[0][1], 0, 0, 0);
        acc[1][0] = __builtin_amdgcn_mfma_f32_16x16x32_bf16(a1, b0, acc[1][0], 0, 0, 0);
        acc[1][1] = __builtin_amdgcn_mfma_f32_16x16x32_bf16(a1, b1, acc[1][1], 0, 0, 0);
    }

#pragma unroll
    for (int fi = 0; fi < 2; fi++)
#pragma unroll
        for (int fj = 0; fj < 2; fj++)
#pragma unroll
            for (int r = 0; r < 4; r++) {
                int row = row0 + wrr + fi * 16 + (lane >> 4) * 4 + r;
                int col = col0 + wcc + fj * 16 + (lane & 15);
                if (row < M && col < Nw) {
                    float v = acc[fi][fj][r];
                    if (OBF16) Cb[(size_t)row * ldc + col] = f2bf(v);
                    else       Cf[(size_t)row * ldc + col] = v;
                }
            }
}

// ---------------- qkv f32 [900,3456] -> rope(q),rope(k) bf16 [16,900,96], v^T bf16 [16,96,928]
__global__ __launch_bounds__(256) void k_rope(const float* __restrict__ qkv,
                                              const float* __restrict__ cs,
                                              const float* __restrict__ sn,
                                              ushort* __restrict__ q,
                                              ushort* __restrict__ k,
                                              ushort* __restrict__ vt) {
    int idx = blockIdx.x * 256 + threadIdx.x;
    if (idx >= NT * NH * DHP) return;
    int t = idx / (NH * DHP);
    int rem = idx - t * (NH * DHP);
    int h = rem / DHP, d = rem - h * DHP;
    size_t oi = ((size_t)h * NT + t) * DHP + d;
    if (d < DHD) {
        const float* base = qkv + (size_t)t * 3 * EMB;
        float c = cs[t * DHD + d], s = sn[t * DHD + d];
        int   d2 = (d < DHH) ? d + DHH : d - DHH;
        float sg = (d < DHH) ? -1.f : 1.f;
        int e = h * DHD + d;
        float qv = base[e] * c + sg * base[h * DHD + d2] * s;
        float kv = base[EMB + e] * c + sg * base[EMB + h * DHD + d2] * s;
        q[oi] = f2bf(qv);
        k[oi] = f2bf(kv);
        vt[((size_t)h * DHP + d) * KVP + t] = f2bf(base[2 * EMB + e]);
    } else {
        q[oi] = 0;
        k[oi] = 0;
    }
}

// zero v^T pad columns t in [900,928)  (run once; later layers never write pads)
__global__ __launch_bounds__(256) void k_vpad(ushort* __restrict__ vt) {
    int idx = blockIdx.x * 256 + threadIdx.x;
    int tot = NH * DHP * (KVP - NT);
    if (idx >= tot) return;
    int pw = KVP - NT;
    int hd = idx / pw, j = idx - hd * pw;
    vt[(size_t)hd * KVP + NT + j] = 0;
}

// ---------------- softmax: S f32 [16*900][928] -> P bf16 (pad cols zeroed) ----------------
__global__ __launch_bounds__(256) void k_sm(const float* __restrict__ S,
                                            ushort* __restrict__ P) {
    int row = blockIdx.x * 4 + (threadIdx.x >> 6);
    int lane = threadIdx.x & 63;
    const float* sp = S + (size_t)row * KVP;
    ushort* pp = P + (size_t)row * KVP;
    float v[15];
#pragma unroll
    for (int i = 0; i < 15; i++) {
        int kt = lane + i * 64;
        v[i] = (kt < NT) ? sp[kt] : -1e30f;
    }
    float mx = -1e30f;
#pragma unroll
    for (int i = 0; i < 15; i++) mx = fmaxf(mx, v[i]);
    for (int off = 32; off; off >>= 1) mx = fmaxf(mx, __shfl_xor(mx, off, 64));
    float sum = 0.f;
#pragma unroll
    for (int i = 0; i < 15; i++) {
        int kt = lane + i * 64;
        v[i] = (kt < NT) ? __expf(v[i] - mx) : 0.f;
        sum += v[i];
    }
    for (int off = 32; off; off >>= 1) sum += __shfl_xor(sum, off, 64);
    float inv = 1.f / sum;
#pragma unroll
    for (int i = 0; i < 15; i++) {
        int kt = lane + i * 64;
        if (kt < KVP) pp[kt] = f2bf(v[i] * inv);
    }
}

extern "C" void kernel_launch(void* const* d_in, const int* in_sizes, int n_in,
                              void* d_out, int out_size, void* d_ws, size_t ws_size,
                              hipStream_t stream) {
    const float* pix     = (const float*)d_in[0];
    const float* patch_w = (const float*)d_in[1];
    const float* patch_b = (const float*)d_in[2];
    const float* pos_emb = (const float*)d_in[3];
    const float* cosb    = (const float*)d_in[4];
    const float* sinb    = (const float*)d_in[5];
    const float* ln1_w   = (const float*)d_in[6];
    const float* ln1_b   = (const float*)d_in[7];
    const float* qkv_w   = (const float*)d_in[8];
    const float* qkv_b   = (const float*)d_in[9];
    const float* proj_w  = (const float*)d_in[10];
    const float* proj_b  = (const float*)d_in[11];
    const float* ln2_w   = (const float*)d_in[12];
    const float* ln2_b   = (const float*)d_in[13];
    const float* fc1_w   = (const float*)d_in[14];
    const float* fc1_b   = (const float*)d_in[15];
    const float* fc2_w   = (const float*)d_in[16];
    const float* fc2_b   = (const float*)d_in[17];
    const float* dsn_w   = (const float*)d_in[18];
    const float* dsn_b   = (const float*)d_in[19];
    const float* ds1_w   = (const float*)d_in[20];
    const float* ds1_b   = (const float*)d_in[21];
    const float* ds2_w   = (const float*)d_in[22];
    const float* ds2_b   = (const float*)d_in[23];
    const float* mn_w    = (const float*)d_in[24];
    const float* mn_b    = (const float*)d_in[25];
    const float* mf1_w   = (const float*)d_in[26];
    const float* mf1_b   = (const float*)d_in[27];
    const float* mf2_w   = (const float*)d_in[28];
    const float* mf2_b   = (const float*)d_in[29];
    float* out = (float*)d_out;

    // ---- workspace carve ----
    float* wsf = (float*)d_ws;
    size_t off = 0;
    auto af = [&](size_t n) { float* p = wsf + off; off += (n + 3) & ~(size_t)3; return p; };
    float* h    = af((size_t)NT * EMB);
    float* qkv  = af((size_t)NT * 3 * EMB);
    float* part = af((size_t)4 * NT * EMB);       // max split-K partials (S=4 @ N=1152 / ds1 equal)
    float* S    = af((size_t)NH * NT * KVP);      // attention scores f32
    ushort* wsh = (ushort*)(wsf + off);
    size_t hoff = 0;
    auto ah = [&](size_t n) { ushort* p = wsh + hoff; hoff += (n + 7) & ~(size_t)7; return p; };
    ushort* hn  = ah((size_t)NT * EMB);
    ushort* qb  = ah((size_t)NH * NT * DHP);
    ushort* kb  = ah((size_t)NH * NT * DHP);
    ushort* vt  = ah((size_t)NH * DHP * KVP);
    ushort* P   = ah((size_t)NH * NT * KVP);
    ushort* ob  = ah((size_t)NT * EMB);
    ushort* t1  = ah((size_t)NT * FFD);
    ushort* xp  = t1;
    // bf16 weight mirrors
    ushort* w_patch = ah((size_t)EMB * 1536);
    ushort* w_qkv   = ah((size_t)NL * 3 * EMB * EMB);
    ushort* w_proj  = ah((size_t)NL * EMB * EMB);
    ushort* w_fc1   = ah((size_t)NL * FFD * EMB);
    ushort* w_fc2   = ah((size_t)NL * EMB * FFD);
    ushort* w_ds1   = ah((size_t)2 * MHD * MHD);
    ushort* w_ds2   = ah((size_t)2 * OUTD * MHD);
    ushort* w_mf1   = ah((size_t)MHD * MHD);
    ushort* w_mf2   = ah((size_t)OUTD * MHD);

    const long QS = (long)NT * DHP;
    const long VS = (long)DHP * KVP;
    const long SS = (long)NT * KVP;

    const int MB  = (NT + 63) / 64;   // 15
    const int MBm = (NM + 63) / 64;   // 4
    auto fixg = [](int M, int N) { return dim3(((size_t)M * N / 4 + 255) / 256); };
    auto cvt = [&](const float* s, ushort* d, size_t n) {
        k_cvt<<<dim3((unsigned)((n / 4 + 255) / 256)), 256, 0, stream>>>(s, d, (int)(n / 4));
    };

    // ---- weight pre-conversion (once per forward) ----
    cvt(patch_w, w_patch, (size_t)EMB * 1536);
    cvt(qkv_w,   w_qkv,   (size_t)NL * 3 * EMB * EMB);
    cvt(proj_w,  w_proj,  (size_t)NL * EMB * EMB);
    cvt(fc1_w,   w_fc1,   (size_t)NL * FFD * EMB);
    cvt(fc2_w,   w_fc2,   (size_t)NL * EMB * FFD);
    cvt(ds1_w,   w_ds1,   (size_t)2 * MHD * MHD);
    cvt(ds2_w,   w_ds2,   (size_t)2 * OUTD * MHD);
    cvt(mf1_w,   w_mf1,   (size_t)MHD * MHD);
    cvt(mf2_w,   w_mf2,   (size_t)OUTD * MHD);

    k_patch<<<dim3((NT * 1536 + 255) / 256), 256, 0, stream>>>(pix, xp);
    k_vpad<<<dim3((NH * DHP * (KVP - NT) + 255) / 256), 256, 0, stream>>>(vt);
    // patch: M=900 N=1152 K=1536, S=2
    k_bgs<0, 0, 1><<<dim3(MB, EMB / 64, 2), 256, 0, stream>>>(
        xp, w_patch, nullptr, nullptr, nullptr, part, NT, EMB, 1536, 2);
    k_fix<0, 0><<<fixg(NT, EMB), 256, 0, stream>>>(part, patch_b, pos_emb, h, NT, EMB, 2);

    for (int l = 0; l < NL; ++l) {
        k_ln<<<NT, 256, 0, stream>>>(h, ln1_w + l * EMB, ln1_b + l * EMB, hn, EMB);
        // qkv: M=900 N=3456 K=1152, S=1 -> 810 blocks, direct f32 + bias
        k_bgs<0, 0, 0><<<dim3(MB, 3 * EMB / 64, 1), 256, 0, stream>>>(
            hn, w_qkv + (size_t)l * 3 * EMB * EMB, qkv_b + l * 3 * EMB, nullptr, qkv,
            nullptr, NT, 3 * EMB, EMB, 1);
        k_rope<<<dim3((NT * NH * DHP + 255) / 256), 256, 0, stream>>>(
            qkv, cosb, sinb, qb, kb, vt);
        // S = Q @ K^T (per head)
        k_mm<0><<<dim3(MB, MB, NH), 256, 0, stream>>>(
            qb, kb, S, NT, NT, DHP, KVP, NT, QS, QS, SS);
        k_sm<<<dim3(NH * NT / 4), 256, 0, stream>>>(S, P);
        // O = P @ V (per head) -> ob bf16 [900][1152]
        k_mm<1><<<dim3(2, MB, NH), 256, 0, stream>>>(
            P, vt, ob, NT, DHD, KVP, EMB, DHD, SS, VS, DHD);
        // proj: M=900 N=1152 K=1152, S=3
        k_bgs<0, 0, 1><<<dim3(MB, EMB / 64, 3), 256, 0, stream>>>(
            ob, w_proj + (size_t)l * EMB * EMB, nullptr, nullptr, nullptr, part,
            NT, EMB, EMB, 3);
        k_fix<0, 0><<<fixg(NT, EMB), 256, 0, stream>>>(part, proj_b + l * EMB, h, h,
                                                       NT, EMB, 3);
        k_ln<<<NT, 256, 0, stream>>>(h, ln2_w + l * EMB, ln2_b + l * EMB, hn, EMB);
        // fc1: M=900 N=4608 K=1152, S=1 -> 1080 blocks, direct gelu bf16
        k_bgs<1, 1, 0><<<dim3(MB, FFD / 64, 1), 256, 0, stream>>>(
            hn, w_fc1 + (size_t)l * FFD * EMB, fc1_b + l * FFD, nullptr, t1,
            nullptr, NT, FFD, EMB, 1);
        // fc2: M=900 N=1152 K=4608, S=4
        k_bgs<0, 0, 1><<<dim3(MB, EMB / 64, 4), 256, 0, stream>>>(
            t1, w_fc2 + (size_t)l * EMB * FFD, nullptr, nullptr, nullptr, part,
            NT, EMB, FFD, 4);
        k_fix<0, 0><<<fixg(NT, EMB), 256, 0, stream>>>(part, fc2_b + l * EMB, h, h,
                                                       NT, EMB, 4);
        if (l == 2 || l == 5) {
            int d = (l == 2) ? 0 : 1;
            k_ln<<<NM, 256, 0, stream>>>(h, dsn_w + d * MHD, dsn_b + d * MHD, hn, MHD);
            // ds1: M=225 N=4608 K=4608, S=4
            k_bgs<0, 0, 1><<<dim3(MBm, MHD / 64, 4), 256, 0, stream>>>(
                hn, w_ds1 + (size_t)d * MHD * MHD, nullptr, nullptr, nullptr, part,
                NM, MHD, MHD, 4);
            k_fix<1, 1><<<fixg(NM, MHD), 256, 0, stream>>>(part, ds1_b + d * MHD,
                                                           nullptr, t1, NM, MHD, 4);
            // ds2: M=225 N=2048 K=4608, S=4
            k_bgs<0, 0, 1><<<dim3(MBm, OUTD / 64, 4), 256, 0, stream>>>(
                t1, w_ds2 + (size_t)d * OUTD * MHD, nullptr, nullptr, nullptr, part,
                NM, OUTD, MHD, 4);
            k_fix<0, 0><<<fixg(NM, OUTD), 256, 0, stream>>>(
                part, ds2_b + d * OUTD, nullptr, out + (size_t)d * NM * OUTD,
                NM, OUTD, 4);
        }
    }
    // merger LN is over EMB=1152 per token (900 rows), THEN reshaped to [225][4608]
    k_ln<<<NT, 256, 0, stream>>>(h, mn_w, mn_b, hn, EMB);
    k_bgs<0, 0, 1><<<dim3(MBm, MHD / 64, 4), 256, 0, stream>>>(
        hn, w_mf1, nullptr, nullptr, nullptr, part, NM, MHD, MHD, 4);
    k_fix<1, 1><<<fixg(NM, MHD), 256, 0, stream>>>(part, mf1_b, nullptr, t1, NM, MHD, 4);
    k_bgs<0, 0, 1><<<dim3(MBm, OUTD / 64, 4), 256, 0, stream>>>(
        t1, w_mf2, nullptr, nullptr, nullptr, part, NM, OUTD, MHD, 4);
    k_fix<0, 0><<<fixg(NM, OUTD), 256, 0, stream>>>(
        part, mf2_b, nullptr, out + (size_t)2 * NM * OUTD, NM, OUTD, 4);
}

// Round 12
// 1441.745 us; speedup vs baseline: 1.1285x; 1.1285x over previous
//
#include <hip/hip_runtime.h>
#include <hip/hip_bf16.h>
#include <cstdint>

#define NT   900
#define EMB  1152
#define NH   16
#define DHD  72
#define DHH  36
#define DHP  96      // padded head dim (3*32)
#define KVP  928     // padded kv length (29*32)
#define NL   6
#define FFD  4608
#define MHD  4608
#define OUTD 2048
#define NM   225

typedef __attribute__((ext_vector_type(8))) short short8;
typedef __attribute__((ext_vector_type(4))) float f32x4;

__device__ __forceinline__ ushort f2bf(float f) {
    uint32_t u = __float_as_uint(f);
    uint32_t r = u + 0x7FFF + ((u >> 16) & 1);
    return (ushort)(r >> 16);
}
__device__ __forceinline__ float gelu_f(float x) {
    return 0.5f * x * (1.0f + tanhf(0.7978845608f * (x + 0.044715f * x * x * x)));
}

// async global -> LDS, 16B per lane (lds dest must be wave-uniform base; HW adds lane*16)
__device__ __forceinline__ void g2lds16(const ushort* g, ushort* l) {
    __builtin_amdgcn_global_load_lds(
        (const __attribute__((address_space(1))) unsigned int*)g,
        (__attribute__((address_space(3))) unsigned int*)l, 16, 0, 0);
}

// ---------------- weight f32 -> bf16 pre-conversion ----------------
__global__ __launch_bounds__(256) void k_cvt(const float* __restrict__ src,
                                             ushort* __restrict__ dst, int n4) {
    int idx = blockIdx.x * 256 + threadIdx.x;
    if (idx >= n4) return;
    const float4 v = *(const float4*)(src + (size_t)idx * 4);
    ushort o[4] = { f2bf(v.x), f2bf(v.y), f2bf(v.z), f2bf(v.w) };
    *(uint2*)(dst + (size_t)idx * 4) = *(const uint2*)o;
}

// ---------------- patch extraction: pixels -> bf16 [900, 1536] ----------------
__global__ __launch_bounds__(256) void k_patch(const float* __restrict__ pix,
                                               ushort* __restrict__ xp) {
    int idx = blockIdx.x * 256 + threadIdx.x;
    if (idx >= NT * 1536) return;
    int t = idx / 1536, f = idx - t * 1536;
    int mw = t & 1, mh = (t >> 1) & 1;
    int tq = t >> 2;
    int jj = tq % 15, ii = tq / 15;
    int pw = f & 15, ph = (f >> 4) & 15, c = f >> 9;
    int Hi = (ii * 2 + mh) * 16 + ph;
    int Wi = (jj * 2 + mw) * 16 + pw;
    float p = pix[((size_t)c * 480 + Hi) * 480 + Wi];
    xp[idx] = f2bf((p - 127.5f) * (1.0f / 127.5f));
}

// ---------------- layernorm f32 in -> bf16 out, one block per row ----------------
__global__ __launch_bounds__(256) void k_ln(const float* __restrict__ x,
                                            const float* __restrict__ w,
                                            const float* __restrict__ b,
                                            ushort* __restrict__ y, int C) {
    int row = blockIdx.x;
    int tid = threadIdx.x;
    const float* xr = x + (size_t)row * C;
    float s = 0.f, ss = 0.f;
    for (int c = tid; c < C; c += 256) { float v = xr[c]; s += v; ss += v * v; }
    for (int off = 32; off; off >>= 1) {
        s  += __shfl_down(s,  off, 64);
        ss += __shfl_down(ss, off, 64);
    }
    __shared__ float rs[4], rss[4];
    int wid = tid >> 6, lane = tid & 63;
    if (lane == 0) { rs[wid] = s; rss[wid] = ss; }
    __syncthreads();
    float S  = rs[0] + rs[1] + rs[2] + rs[3];
    float SS = rss[0] + rss[1] + rss[2] + rss[3];
    float mu  = S / C;
    float var = SS / C - mu * mu;
    float inv = rsqrtf(var + 1e-6f);
    ushort* yr = y + (size_t)row * C;
    for (int c = tid; c < C; c += 256) yr[c] = f2bf((xr[c] - mu) * inv * w[c] + b[c]);
}

// ---------------- fused split-K reduce + bias + residual + LayerNorm ----------------
// One block per row. C <= 2048 (uses 2 float4 per thread). Writes h (f32) and hn (bf16).
__global__ __launch_bounds__(256) void k_fixln(const float* __restrict__ part,
                                               const float* __restrict__ bias,
                                               const float* __restrict__ res,
                                               float* __restrict__ hout,
                                               const float* __restrict__ lw,
                                               const float* __restrict__ lb,
                                               ushort* __restrict__ y,
                                               int C, int S, long MN) {
    int row = blockIdx.x, tid = threadIdx.x;
    int C4 = C >> 2;
    const float* prow = part + (size_t)row * C;
    const float* rrow = res + (size_t)row * C;
    float* hrow = hout + (size_t)row * C;
    ushort* yrow = y + (size_t)row * C;

    float4 vals[2];
    float s = 0.f, ss = 0.f;
    int idx[2] = { tid, tid + 256 };
#pragma unroll
    for (int it = 0; it < 2; ++it) {
        int c4 = idx[it];
        if (c4 < C4) {
            float4 v = *(const float4*)(prow + c4 * 4);
            for (int sI = 1; sI < S; ++sI) {
                const float4 p = *(const float4*)(prow + (size_t)sI * MN + c4 * 4);
                v.x += p.x; v.y += p.y; v.z += p.z; v.w += p.w;
            }
            const float4 bi = *(const float4*)(bias + c4 * 4);
            v.x += bi.x; v.y += bi.y; v.z += bi.z; v.w += bi.w;
            const float4 rr = *(const float4*)(rrow + c4 * 4);
            v.x += rr.x; v.y += rr.y; v.z += rr.z; v.w += rr.w;
            *(float4*)(hrow + c4 * 4) = v;
            vals[it] = v;
            s  += v.x + v.y + v.z + v.w;
            ss += v.x * v.x + v.y * v.y + v.z * v.z + v.w * v.w;
        }
    }
    for (int off = 32; off; off >>= 1) {
        s  += __shfl_down(s,  off, 64);
        ss += __shfl_down(ss, off, 64);
    }
    __shared__ float rs[4], rss[4];
    int wid = tid >> 6, lane = tid & 63;
    if (lane == 0) { rs[wid] = s; rss[wid] = ss; }
    __syncthreads();
    float St  = rs[0] + rs[1] + rs[2] + rs[3];
    float SSt = rss[0] + rss[1] + rss[2] + rss[3];
    float mu  = St / C;
    float var = SSt / C - mu * mu;
    float inv = rsqrtf(var + 1e-6f);
#pragma unroll
    for (int it = 0; it < 2; ++it) {
        int c4 = idx[it];
        if (c4 < C4) {
            float4 v = vals[it];
            const float4 w4 = *(const float4*)(lw + c4 * 4);
            const float4 b4 = *(const float4*)(lb + c4 * 4);
            ushort o[4] = { f2bf((v.x - mu) * inv * w4.x + b4.x),
                            f2bf((v.y - mu) * inv * w4.y + b4.y),
                            f2bf((v.z - mu) * inv * w4.z + b4.z),
                            f2bf((v.w - mu) * inv * w4.w + b4.w) };
            *(uint2*)(yrow + c4 * 4) = *(const uint2*)o;
        }
    }
}

// ---------------- dense MFMA GEMM, 64x64 tile, BK=64, global_load_lds + XOR swizzle
// C[M,N] = act(A[M,K](bf16) @ W[N,K]^T(bf16) + bias) + res   (N % 64 == 0)
// grid (ceil(M/64), N/64, S). SPLIT=1: raw partials to part[z][M][N].
// LDS physical layout: row r, granule g (8 elems) holds global granule g ^ (r&7).
template <int ACT, int OBF16, int SPLIT>
__global__ __launch_bounds__(256) void k_bgs(const ushort* __restrict__ A,
                                             const ushort* __restrict__ W,
                                             const float* __restrict__ bias,
                                             const float* __restrict__ res,
                                             void* __restrict__ Cp,
                                             float* __restrict__ part,
                                             int M, int N, int K, int S) {
    __shared__ __align__(16) ushort As[64 * 64];
    __shared__ __align__(16) ushort Bs[64 * 64];
    int tid = threadIdx.x;
    int row0 = blockIdx.x * 64, col0 = blockIdx.y * 64;
    int z = blockIdx.z;
    int Kc = K / S;              // multiple of 64
    int kbeg = z * Kc;
    int steps = Kc >> 6;

    int w = tid >> 6, lane = tid & 63;
    int lrow = lane >> 3;                    // 0..7
    int cg   = ((lane & 7) ^ lrow) << 3;     // pre-swizzled source granule (elems)

    // staging rows: wave w covers rows [w*16, w*16+16) in two 8-row issues
    int ar0 = row0 + w * 16 + lrow; if (ar0 > M - 1) ar0 = M - 1;
    int ar1 = row0 + w * 16 + 8 + lrow; if (ar1 > M - 1) ar1 = M - 1;
    int wr0 = col0 + w * 16 + lrow;          // N multiple of 64 -> in range
    int wr1 = wr0 + 8;
    const ushort* ap0 = A + (size_t)ar0 * K + kbeg + cg;
    const ushort* ap1 = A + (size_t)ar1 * K + kbeg + cg;
    const ushort* wp0 = W + (size_t)wr0 * K + kbeg + cg;
    const ushort* wp1 = W + (size_t)wr1 * K + kbeg + cg;
    ushort* asd0 = &As[(w * 16) * 64];
    ushort* asd1 = &As[(w * 16 + 8) * 64];
    ushort* bsd0 = &Bs[(w * 16) * 64];
    ushort* bsd1 = &Bs[(w * 16 + 8) * 64];

    int fr = lane & 15, kg8 = (lane >> 4) << 3;
    int wrr = (w >> 1) * 32, wcc = (w & 1) * 32;
    int sw = (fr & 7) << 3;                  // ds_read granule XOR (elems)

    f32x4 acc[2][2] = {};
    for (int s = 0; s < steps; ++s) {
        int kk = s << 6;
        __syncthreads();                     // prior tile fully consumed
        g2lds16(ap0 + kk, asd0);
        g2lds16(ap1 + kk, asd1);
        g2lds16(wp0 + kk, bsd0);
        g2lds16(wp1 + kk, bsd1);
        __syncthreads();                     // drains vmcnt: tile resident
#pragma unroll
        for (int j = 0; j < 2; ++j) {
            int ko = j * 32 + kg8;
            int kx = ko ^ sw;
            short8 a0 = *(const short8*)&As[(wrr + fr) * 64 + kx];
            short8 a1 = *(const short8*)&As[(wrr + 16 + fr) * 64 + kx];
            short8 b0 = *(const short8*)&Bs[(wcc + fr) * 64 + kx];
            short8 b1 = *(const short8*)&Bs[(wcc + 16 + fr) * 64 + kx];
            acc[0][0] = __builtin_amdgcn_mfma_f32_16x16x32_bf16(a0, b0, acc[0][0], 0, 0, 0);
            acc[0][1] = __builtin_amdgcn_mfma_f32_16x16x32_bf16(a0, b1, acc[0][1], 0, 0, 0);
            acc[1][0] = __builtin_amdgcn_mfma_f32_16x16x32_bf16(a1, b0, acc[1][0], 0, 0, 0);
            acc[1][1] = __builtin_amdgcn_mfma_f32_16x16x32_bf16(a1, b1, acc[1][1], 0, 0, 0);
        }
    }

#pragma unroll
    for (int fi = 0; fi < 2; fi++)
#pragma unroll
        for (int fj = 0; fj < 2; fj++)
#pragma unroll
            for (int r = 0; r < 4; r++) {
                int row = row0 + wrr + fi * 16 + (lane >> 4) * 4 + r;
                int col = col0 + wcc + fj * 16 + fr;
                if (row < M) {
                    if (SPLIT) {
                        part[((size_t)z * M + row) * N + col] = acc[fi][fj][r];
                    } else {
                        float v = acc[fi][fj][r] + bias[col];
                        if (res) v += res[(size_t)row * N + col];
                        if (ACT == 1) v = gelu_f(v);
                        if (OBF16) ((ushort*)Cp)[(size_t)row * N + col] = f2bf(v);
                        else       ((float*)Cp)[(size_t)row * N + col] = v;
                    }
                }
            }
}

// ---------------- split-K fixup (no LN) ----------------
template <int ACT, int OBF16>
__global__ __launch_bounds__(256) void k_fix(const float* __restrict__ part,
                                             const float* __restrict__ bias,
                                             const float* __restrict__ res,
                                             void* __restrict__ Cp,
                                             int M, int N, int S) {
    size_t idx = (size_t)blockIdx.x * 256 + threadIdx.x;
    size_t total = (size_t)M * N / 4;
    if (idx >= total) return;
    size_t e = idx * 4;
    int row = (int)(e / N), col = (int)(e - (size_t)row * N);
    float4 v = *(const float4*)(part + e);
    for (int s = 1; s < S; ++s) {
        const float4 p = *(const float4*)(part + (size_t)s * M * N + e);
        v.x += p.x; v.y += p.y; v.z += p.z; v.w += p.w;
    }
    const float4 bi = *(const float4*)(bias + col);
    v.x += bi.x; v.y += bi.y; v.z += bi.z; v.w += bi.w;
    if (res) {
        const float4 rr = *(const float4*)(res + e);
        v.x += rr.x; v.y += rr.y; v.z += rr.z; v.w += rr.w;
    }
    if (ACT == 1) { v.x = gelu_f(v.x); v.y = gelu_f(v.y); v.z = gelu_f(v.z); v.w = gelu_f(v.w); }
    if (OBF16) {
        ushort o[4] = { f2bf(v.x), f2bf(v.y), f2bf(v.z), f2bf(v.w) };
        *(uint2*)((ushort*)Cp + e) = *(const uint2*)o;
    } else {
        *(float4*)((float*)Cp + e) = v;
    }
}

// ---------------- attention GEMM (bf16 A & W, batched over heads), BK=32 ----
template <int OBF16>
__global__ __launch_bounds__(256) void k_mm(const ushort* __restrict__ A,
                                            const ushort* __restrict__ Wb,
                                            void* __restrict__ Cp,
                                            int M, int N, int K, int ldc, int Nw,
                                            long as_, long ws_, long cs_) {
    __shared__ __align__(16) ushort As[64 * 40];
    __shared__ __align__(16) ushort Bs[64 * 40];
    int z = blockIdx.z;
    A  += (size_t)z * as_;
    Wb += (size_t)z * ws_;
    float*  Cf = (float*)Cp + (size_t)z * cs_;
    ushort* Cb = (ushort*)Cp + (size_t)z * cs_;

    int tid = threadIdx.x;
    int row0 = blockIdx.y * 64, col0 = blockIdx.x * 64;

    int sm = tid >> 2, sp = tid & 3;
    int ar = row0 + sm; if (ar > M - 1) ar = M - 1;
    int wr = col0 + sm; if (wr > N - 1) wr = N - 1;
    const ushort* aptr = A + (size_t)ar * K;

    int lane = tid & 63, wid = tid >> 6;
    int wrr = (wid >> 1) * 32, wcc = (wid & 1) * 32;
    int fr = lane & 15, kg = lane >> 4;

    f32x4 acc[2][2] = {};

    for (int k0 = 0; k0 < K; k0 += 32) {
        *(uint4*)&As[sm * 40 + sp * 8] = *(const uint4*)(aptr + k0 + sp * 8);
        *(uint4*)&Bs[sm * 40 + sp * 8] = *(const uint4*)(Wb + (size_t)wr * K + k0 + sp * 8);
        __syncthreads();
        short8 a0 = *(const short8*)&As[(wrr + fr) * 40 + kg * 8];
        short8 a1 = *(const short8*)&As[(wrr + 16 + fr) * 40 + kg * 8];
        short8 b0 = *(const short8*)&Bs[(wcc + fr) * 40 + kg * 8];
        short8 b1 = *(const short8*)&Bs[(wcc + 16 + fr) * 40 + kg * 8];
        acc[0][0] = __builtin_amdgcn_mfma_f32_16x16x32_bf16(a0, b0, acc[0][0], 0, 0, 0);
        acc[0][1] = __builtin_amdgcn_mfma_f32_16x16x32_bf16(a0, b1, acc[0][1], 0, 0, 0);
        acc[1][0] = __builtin_amdgcn_mfma_f32_16x16x32_bf16(a1, b0, acc[1][0], 0, 0, 0);
        acc[1][1] = __builtin_amdgcn_mfma_f32_16x16x32_bf16(a1, b1, acc[1][1], 0, 0, 0);
        __syncthreads();
    }

#pragma unroll
    for (int fi = 0; fi < 2; fi++)
#pragma unroll
        for (int fj = 0; fj < 2; fj++)
#pragma unroll
            for (int r = 0; r < 4; r++) {
                int row = row0 + wrr + fi * 16 + (lane >> 4) * 4 + r;
                int col = col0 + wcc + fj * 16 + (lane & 15);
                if (row < M && col < Nw) {
                    float v = acc[fi][fj][r];
                    if (OBF16) Cb[(size_t)row * ldc + col] = f2bf(v);
                    else       Cf[(size_t)row * ldc + col] = v;
                }
            }
}

// ---------------- qkv f32 [900,3456] -> rope(q),rope(k) bf16 [16,900,96], v^T bf16 [16,96,928]
__global__ __launch_bounds__(256) void k_rope(const float* __restrict__ qkv,
                                              const float* __restrict__ cs,
                                              const float* __restrict__ sn,
                                              ushort* __restrict__ q,
                                              ushort* __restrict__ k,
                                              ushort* __restrict__ vt) {
    int idx = blockIdx.x * 256 + threadIdx.x;
    if (idx >= NT * NH * DHP) return;
    int t = idx / (NH * DHP);
    int rem = idx - t * (NH * DHP);
    int h = rem / DHP, d = rem - h * DHP;
    size_t oi = ((size_t)h * NT + t) * DHP + d;
    if (d < DHD) {
        const float* base = qkv + (size_t)t * 3 * EMB;
        float c = cs[t * DHD + d], s = sn[t * DHD + d];
        int   d2 = (d < DHH) ? d + DHH : d - DHH;
        float sg = (d < DHH) ? -1.f : 1.f;
        int e = h * DHD + d;
        float qv = base[e] * c + sg * base[h * DHD + d2] * s;
        float kv = base[EMB + e] * c + sg * base[EMB + h * DHD + d2] * s;
        q[oi] = f2bf(qv);
        k[oi] = f2bf(kv);
        vt[((size_t)h * DHP + d) * KVP + t] = f2bf(base[2 * EMB + e]);
    } else {
        q[oi] = 0;
        k[oi] = 0;
    }
}

// zero v^T pad columns t in [900,928)  (run once; later layers never write pads)
__global__ __launch_bounds__(256) void k_vpad(ushort* __restrict__ vt) {
    int idx = blockIdx.x * 256 + threadIdx.x;
    int tot = NH * DHP * (KVP - NT);
    if (idx >= tot) return;
    int pw = KVP - NT;
    int hd = idx / pw, j = idx - hd * pw;
    vt[(size_t)hd * KVP + NT + j] = 0;
}

// ---------------- softmax: S f32 [16*900][928] -> P bf16 (pad cols zeroed) ----------------
__global__ __launch_bounds__(256) void k_sm(const float* __restrict__ S,
                                            ushort* __restrict__ P) {
    int row = blockIdx.x * 4 + (threadIdx.x >> 6);
    int lane = threadIdx.x & 63;
    const float* sp = S + (size_t)row * KVP;
    ushort* pp = P + (size_t)row * KVP;
    float v[15];
#pragma unroll
    for (int i = 0; i < 15; i++) {
        int kt = lane + i * 64;
        v[i] = (kt < NT) ? sp[kt] : -1e30f;
    }
    float mx = -1e30f;
#pragma unroll
    for (int i = 0; i < 15; i++) mx = fmaxf(mx, v[i]);
    for (int off = 32; off; off >>= 1) mx = fmaxf(mx, __shfl_xor(mx, off, 64));
    float sum = 0.f;
#pragma unroll
    for (int i = 0; i < 15; i++) {
        int kt = lane + i * 64;
        v[i] = (kt < NT) ? __expf(v[i] - mx) : 0.f;
        sum += v[i];
    }
    for (int off = 32; off; off >>= 1) sum += __shfl_xor(sum, off, 64);
    float inv = 1.f / sum;
#pragma unroll
    for (int i = 0; i < 15; i++) {
        int kt = lane + i * 64;
        if (kt < KVP) pp[kt] = f2bf(v[i] * inv);
    }
}

extern "C" void kernel_launch(void* const* d_in, const int* in_sizes, int n_in,
                              void* d_out, int out_size, void* d_ws, size_t ws_size,
                              hipStream_t stream) {
    const float* pix     = (const float*)d_in[0];
    const float* patch_w = (const float*)d_in[1];
    const float* patch_b = (const float*)d_in[2];
    const float* pos_emb = (const float*)d_in[3];
    const float* cosb    = (const float*)d_in[4];
    const float* sinb    = (const float*)d_in[5];
    const float* ln1_w   = (const float*)d_in[6];
    const float* ln1_b   = (const float*)d_in[7];
    const float* qkv_w   = (const float*)d_in[8];
    const float* qkv_b   = (const float*)d_in[9];
    const float* proj_w  = (const float*)d_in[10];
    const float* proj_b  = (const float*)d_in[11];
    const float* ln2_w   = (const float*)d_in[12];
    const float* ln2_b   = (const float*)d_in[13];
    const float* fc1_w   = (const float*)d_in[14];
    const float* fc1_b   = (const float*)d_in[15];
    const float* fc2_w   = (const float*)d_in[16];
    const float* fc2_b   = (const float*)d_in[17];
    const float* dsn_w   = (const float*)d_in[18];
    const float* dsn_b   = (const float*)d_in[19];
    const float* ds1_w   = (const float*)d_in[20];
    const float* ds1_b   = (const float*)d_in[21];
    const float* ds2_w   = (const float*)d_in[22];
    const float* ds2_b   = (const float*)d_in[23];
    const float* mn_w    = (const float*)d_in[24];
    const float* mn_b    = (const float*)d_in[25];
    const float* mf1_w   = (const float*)d_in[26];
    const float* mf1_b   = (const float*)d_in[27];
    const float* mf2_w   = (const float*)d_in[28];
    const float* mf2_b   = (const float*)d_in[29];
    float* out = (float*)d_out;

    // ---- workspace carve ----
    float* wsf = (float*)d_ws;
    size_t off = 0;
    auto af = [&](size_t n) { float* p = wsf + off; off += (n + 3) & ~(size_t)3; return p; };
    float* h    = af((size_t)NT * EMB);
    float* qkv  = af((size_t)NT * 3 * EMB);
    float* part = af((size_t)4 * NT * EMB);       // max split-K partials (S=4 @ [900][1152] / ds1 equal)
    float* S    = af((size_t)NH * NT * KVP);      // attention scores f32
    ushort* wsh = (ushort*)(wsf + off);
    size_t hoff = 0;
    auto ah = [&](size_t n) { ushort* p = wsh + hoff; hoff += (n + 7) & ~(size_t)7; return p; };
    ushort* hn  = ah((size_t)NT * EMB);           // ln1/ln2/merger-ln output
    ushort* hn2 = ah((size_t)NM * MHD);           // deepstack-ln output
    ushort* qb  = ah((size_t)NH * NT * DHP);
    ushort* kb  = ah((size_t)NH * NT * DHP);
    ushort* vt  = ah((size_t)NH * DHP * KVP);
    ushort* P   = ah((size_t)NH * NT * KVP);
    ushort* ob  = ah((size_t)NT * EMB);
    ushort* t1  = ah((size_t)NT * FFD);
    ushort* xp  = t1;
    // bf16 weight mirrors
    ushort* w_patch = ah((size_t)EMB * 1536);
    ushort* w_qkv   = ah((size_t)NL * 3 * EMB * EMB);
    ushort* w_proj  = ah((size_t)NL * EMB * EMB);
    ushort* w_fc1   = ah((size_t)NL * FFD * EMB);
    ushort* w_fc2   = ah((size_t)NL * EMB * FFD);
    ushort* w_ds1   = ah((size_t)2 * MHD * MHD);
    ushort* w_ds2   = ah((size_t)2 * OUTD * MHD);
    ushort* w_mf1   = ah((size_t)MHD * MHD);
    ushort* w_mf2   = ah((size_t)OUTD * MHD);

    const long QS = (long)NT * DHP;
    const long VS = (long)DHP * KVP;
    const long SS = (long)NT * KVP;
    const long MN = (long)NT * EMB;               // part slice stride for [900][1152] users

    const int MB  = (NT + 63) / 64;   // 15
    const int MBm = (NM + 63) / 64;   // 4
    auto fixg = [](int M, int N) { return dim3(((size_t)M * N / 4 + 255) / 256); };
    auto cvt = [&](const float* s, ushort* d, size_t n) {
        k_cvt<<<dim3((unsigned)((n / 4 + 255) / 256)), 256, 0, stream>>>(s, d, (int)(n / 4));
    };

    // ---- weight pre-conversion (once per forward) ----
    cvt(patch_w, w_patch, (size_t)EMB * 1536);
    cvt(qkv_w,   w_qkv,   (size_t)NL * 3 * EMB * EMB);
    cvt(proj_w,  w_proj,  (size_t)NL * EMB * EMB);
    cvt(fc1_w,   w_fc1,   (size_t)NL * FFD * EMB);
    cvt(fc2_w,   w_fc2,   (size_t)NL * EMB * FFD);
    cvt(ds1_w,   w_ds1,   (size_t)2 * MHD * MHD);
    cvt(ds2_w,   w_ds2,   (size_t)2 * OUTD * MHD);
    cvt(mf1_w,   w_mf1,   (size_t)MHD * MHD);
    cvt(mf2_w,   w_mf2,   (size_t)OUTD * MHD);

    k_patch<<<dim3((NT * 1536 + 255) / 256), 256, 0, stream>>>(pix, xp);
    k_vpad<<<dim3((NH * DHP * (KVP - NT) + 255) / 256), 256, 0, stream>>>(vt);
    // patch: M=900 N=1152 K=1536, S=2; fused epilogue: +pos_emb, write h, then ln1[0] -> hn
    k_bgs<0, 0, 1><<<dim3(MB, EMB / 64, 2), 256, 0, stream>>>(
        xp, w_patch, nullptr, nullptr, nullptr, part, NT, EMB, 1536, 2);
    k_fixln<<<NT, 256, 0, stream>>>(part, patch_b, pos_emb, h,
                                    ln1_w, ln1_b, hn, EMB, 2, MN);

    for (int l = 0; l < NL; ++l) {
        // hn holds ln1[l] output already
        // qkv: M=900 N=3456 K=1152, S=1 -> 810 blocks, direct f32 + bias
        k_bgs<0, 0, 0><<<dim3(MB, 3 * EMB / 64, 1), 256, 0, stream>>>(
            hn, w_qkv + (size_t)l * 3 * EMB * EMB, qkv_b + l * 3 * EMB, nullptr, qkv,
            nullptr, NT, 3 * EMB, EMB, 1);
        k_rope<<<dim3((NT * NH * DHP + 255) / 256), 256, 0, stream>>>(
            qkv, cosb, sinb, qb, kb, vt);
        // S = Q @ K^T (per head)
        k_mm<0><<<dim3(MB, MB, NH), 256, 0, stream>>>(
            qb, kb, S, NT, NT, DHP, KVP, NT, QS, QS, SS);
        k_sm<<<dim3(NH * NT / 4), 256, 0, stream>>>(S, P);
        // O = P @ V (per head) -> ob bf16 [900][1152]
        k_mm<1><<<dim3(2, MB, NH), 256, 0, stream>>>(
            P, vt, ob, NT, DHD, KVP, EMB, DHD, SS, VS, DHD);
        // proj: M=900 N=1152 K=1152, S=3; fused: +h residual, write h, then ln2 -> hn
        k_bgs<0, 0, 1><<<dim3(MB, EMB / 64, 3), 256, 0, stream>>>(
            ob, w_proj + (size_t)l * EMB * EMB, nullptr, nullptr, nullptr, part,
            NT, EMB, EMB, 3);
        k_fixln<<<NT, 256, 0, stream>>>(part, proj_b + l * EMB, h, h,
                                        ln2_w + l * EMB, ln2_b + l * EMB, hn,
                                        EMB, 3, MN);
        // fc1: M=900 N=4608 K=1152, S=1 -> 1080 blocks, direct gelu bf16
        k_bgs<1, 1, 0><<<dim3(MB, FFD / 64, 1), 256, 0, stream>>>(
            hn, w_fc1 + (size_t)l * FFD * EMB, fc1_b + l * FFD, nullptr, t1,
            nullptr, NT, FFD, EMB, 1);
        // fc2: M=900 N=1152 K=4608, S=4; fused: +h residual, write h, then ln1[l+1]
        // (or merger-ln after the last layer) -> hn
        const float* nlw = (l == NL - 1) ? mn_w : ln1_w + (l + 1) * EMB;
        const float* nlb = (l == NL - 1) ? mn_b : ln1_b + (l + 1) * EMB;
        k_bgs<0, 0, 1><<<dim3(MB, EMB / 64, 4), 256, 0, stream>>>(
            t1, w_fc2 + (size_t)l * EMB * FFD, nullptr, nullptr, nullptr, part,
            NT, EMB, FFD, 4);
        k_fixln<<<NT, 256, 0, stream>>>(part, fc2_b + l * EMB, h, h,
                                        nlw, nlb, hn, EMB, 4, MN);
        if (l == 2 || l == 5) {
            int d = (l == 2) ? 0 : 1;
            k_ln<<<NM, 256, 0, stream>>>(h, dsn_w + d * MHD, dsn_b + d * MHD, hn2, MHD);
            // ds1: M=225 N=4608 K=4608, S=4
            k_bgs<0, 0, 1><<<dim3(MBm, MHD / 64, 4), 256, 0, stream>>>(
                hn2, w_ds1 + (size_t)d * MHD * MHD, nullptr, nullptr, nullptr, part,
                NM, MHD, MHD, 4);
            k_fix<1, 1><<<fixg(NM, MHD), 256, 0, stream>>>(part, ds1_b + d * MHD,
                                                           nullptr, t1, NM, MHD, 4);
            // ds2: M=225 N=2048 K=4608, S=4
            k_bgs<0, 0, 1><<<dim3(MBm, OUTD / 64, 4), 256, 0, stream>>>(
                t1, w_ds2 + (size_t)d * OUTD * MHD, nullptr, nullptr, nullptr, part,
                NM, OUTD, MHD, 4);
            k_fix<0, 0><<<fixg(NM, OUTD), 256, 0, stream>>>(
                part, ds2_b + d * OUTD, nullptr, out + (size_t)d * NM * OUTD,
                NM, OUTD, 4);
        }
    }
    // merger: hn already holds merger-LN output ([900][1152] == [225][4608])
    k_bgs<0, 0, 1><<<dim3(MBm, MHD / 64, 4), 256, 0, stream>>>(
        hn, w_mf1, nullptr, nullptr, nullptr, part, NM, MHD, MHD, 4);
    k_fix<1, 1><<<fixg(NM, MHD), 256, 0, stream>>>(part, mf1_b, nullptr, t1, NM, MHD, 4);
    k_bgs<0, 0, 1><<<dim3(MBm, OUTD / 64, 4), 256, 0, stream>>>(
        t1, w_mf2, nullptr, nullptr, nullptr, part, NM, OUTD, MHD, 4);
    k_fix<0, 0><<<fixg(NM, OUTD), 256, 0, stream>>>(
        part, mf2_b, nullptr, out + (size_t)2 * NM * OUTD, NM, OUTD, 4);
}